// Round 3
// baseline (265.371 us; speedup 1.0000x reference)
//
#include <hip/hip_runtime.h>
#include <cstdint>

#define LT 24
#define NSITE (LT*LT*LT*LT)   // 331776

struct C3 { float re[9]; float im[9]; };

__device__ __forceinline__ void loadM(C3& m, const float* __restrict__ re,
                                      const float* __restrict__ im, int off) {
#pragma unroll
    for (int j = 0; j < 9; ++j) {
        m.re[j] = re[off + j];
        m.im[j] = im[off + j];
    }
}

// o = a @ b
__device__ __forceinline__ void mmul(C3& o, const C3& a, const C3& b) {
#pragma unroll
    for (int r = 0; r < 3; ++r) {
#pragma unroll
        for (int c = 0; c < 3; ++c) {
            float sr = 0.f, si = 0.f;
#pragma unroll
            for (int k = 0; k < 3; ++k) {
                float ar = a.re[r*3+k], ai = a.im[r*3+k];
                float br = b.re[k*3+c], bi = b.im[k*3+c];
                sr += ar*br - ai*bi;
                si += ar*bi + ai*br;
            }
            o.re[r*3+c] = sr; o.im[r*3+c] = si;
        }
    }
}

// o = a @ b^dagger : o[r][c] = sum_k a[r][k] * conj(b[c][k])
__device__ __forceinline__ void mmul_adjB(C3& o, const C3& a, const C3& b) {
#pragma unroll
    for (int r = 0; r < 3; ++r) {
#pragma unroll
        for (int c = 0; c < 3; ++c) {
            float sr = 0.f, si = 0.f;
#pragma unroll
            for (int k = 0; k < 3; ++k) {
                float ar = a.re[r*3+k], ai = a.im[r*3+k];
                float br = b.re[c*3+k], bi = b.im[c*3+k];
                sr += ar*br + ai*bi;
                si += ai*br - ar*bi;
            }
            o.re[r*3+c] = sr; o.im[r*3+c] = si;
        }
    }
}

// o = a^dagger @ b : o[r][c] = sum_k conj(a[k][r]) * b[k][c]
__device__ __forceinline__ void madjA_mul(C3& o, const C3& a, const C3& b) {
#pragma unroll
    for (int r = 0; r < 3; ++r) {
#pragma unroll
        for (int c = 0; c < 3; ++c) {
            float sr = 0.f, si = 0.f;
#pragma unroll
            for (int k = 0; k < 3; ++k) {
                float ar = a.re[k*3+r], ai = a.im[k*3+r];
                float br = b.re[k*3+c], bi = b.im[k*3+c];
                sr += ar*br + ai*bi;
                si += ar*bi - ai*br;
            }
            o.re[r*3+c] = sr; o.im[r*3+c] = si;
        }
    }
}

__device__ __forceinline__ void macc(C3& f, const C3& s, float cr) {
#pragma unroll
    for (int j = 0; j < 9; ++j) { f.re[j] += cr * s.re[j]; f.im[j] += cr * s.im[j]; }
}

// ---- Kernel 1: f32 re/im planes -> interleaved f32 (re,im), whole field ----
__global__ void interleave_kernel(const float4* __restrict__ re,
                                  const float4* __restrict__ im,
                                  float4* __restrict__ out, int n4) {
    int i = blockIdx.x * blockDim.x + threadIdx.x;
    if (i >= n4) return;
    float4 a = re[i], b = im[i];
    float4 o0, o1;
    o0.x = a.x; o0.y = b.x; o0.z = a.y; o0.w = b.y;
    o1.x = a.z; o1.y = b.z; o1.z = a.w; o1.w = b.w;
    out[2*i]     = o0;
    out[2*i + 1] = o1;
}

// ---- Kernel 2: stout update on dir-0 even sites -----------------------------
__global__ __launch_bounds__(256)
void stout_kernel(const float* __restrict__ xre, const float* __restrict__ xim,
                  const float* __restrict__ coeff, float2* __restrict__ out) {
    int tid = blockIdx.x * blockDim.x + threadIdx.x;
    if (tid >= NSITE / 2) return;

    int xh = tid % 12;  int r0 = tid / 12;
    int y  = r0 % LT;   r0 /= LT;
    int z  = r0 % LT;   int t = r0 / LT;
    int x  = 2 * xh + ((t + z + y) & 1);   // even-parity site

    // scaled coefficients: (2/pi)*0.75*atan(coeff)/6
    float c[6];
#pragma unroll
    for (int i = 0; i < 6; ++i)
        c[i] = 0.07957747154594768f * atanf(coeff[i]);

    int tp = (t + 1 < LT) ? t + 1 : 0;
    int zp = (z + 1 < LT) ? z + 1 : 0;  int zm = (z > 0) ? z - 1 : LT - 1;
    int yp = (y + 1 < LT) ? y + 1 : 0;  int ym = (y > 0) ? y - 1 : LT - 1;
    int xp = (x + 1 < LT) ? x + 1 : 0;  int xm = (x > 0) ? x - 1 : LT - 1;

    const int s   = ((t  * LT + z) * LT + y) * LT + x;
    const int stt = ((tp * LT + z) * LT + y) * LT + x;   // s + T^
    const int spv[3]  = { ((t  * LT + zp) * LT + y ) * LT + x,
                          ((t  * LT + z ) * LT + yp) * LT + x,
                          ((t  * LT + z ) * LT + y ) * LT + xp };
    const int smv[3]  = { ((t  * LT + zm) * LT + y ) * LT + x,
                          ((t  * LT + z ) * LT + ym) * LT + x,
                          ((t  * LT + z ) * LT + y ) * LT + xm };
    const int smtv[3] = { ((tp * LT + zm) * LT + y ) * LT + x,
                          ((tp * LT + z ) * LT + ym) * LT + x,
                          ((tp * LT + z ) * LT + y ) * LT + xm };

    C3 f;
#pragma unroll
    for (int j = 0; j < 9; ++j) { f.re[j] = 0.f; f.im[j] = 0.f; }

    C3 A, B, Cm, tmp, stp;
#pragma unroll
    for (int i = 0; i < 3; ++i) {
        const int d = i + 1;
        // forward staple: x[nu](s) @ x0(s+nu) @ x[nu](s+T)^dag
        loadM(A,  xre, xim, (d * NSITE + s)      * 9);
        loadM(B,  xre, xim, (     spv[i])        * 9);  // dir 0
        loadM(Cm, xre, xim, (d * NSITE + stt)    * 9);
        mmul_adjB(tmp, B, Cm);
        mmul(stp, A, tmp);
        macc(f, stp, c[2 * i]);
        // backward staple: x[nu](s-nu)^dag @ x0(s-nu) @ x[nu](s-nu+T)
        loadM(A,  xre, xim, (d * NSITE + smv[i]) * 9);
        loadM(B,  xre, xim, (     smv[i])        * 9);  // dir 0
        loadM(Cm, xre, xim, (d * NSITE + smtv[i])* 9);
        madjA_mul(tmp, A, B);
        mmul(stp, tmp, Cm);
        macc(f, stp, c[2 * i + 1]);
    }

    // xupd = x0(s) (even site)
    C3 U;
    loadM(U, xre, xim, s * 9);

    // M = f @ U^dag ; A = 0.5(M - M^dag) ; Zt = A - tr(A)/3 * I
    C3 Mm;
    mmul_adjB(Mm, f, U);
    C3 Zt;
#pragma unroll
    for (int r = 0; r < 3; ++r) {
#pragma unroll
        for (int cq = 0; cq < 3; ++cq) {
            Zt.re[r*3+cq] = 0.5f * (Mm.re[r*3+cq] - Mm.re[cq*3+r]);
            Zt.im[r*3+cq] = 0.5f * (Mm.im[r*3+cq] + Mm.im[cq*3+r]);
        }
    }
    float trIm = (Zt.im[0] + Zt.im[4] + Zt.im[8]) / 3.0f;
    Zt.im[0] -= trIm; Zt.im[4] -= trIm; Zt.im[8] -= trIm;

    // matexp: scale by 0.5^4, 12-term Horner, 4 squarings
#pragma unroll
    for (int j = 0; j < 9; ++j) { Zt.re[j] *= 0.0625f; Zt.im[j] *= 0.0625f; }

    C3 E;
#pragma unroll
    for (int j = 0; j < 9; ++j) { E.re[j] = 0.f; E.im[j] = 0.f; }
    E.re[0] = 1.f; E.re[4] = 1.f; E.re[8] = 1.f;

    C3 Tm;
#pragma unroll
    for (int k = 12; k >= 1; --k) {
        mmul(Tm, Zt, E);
        const float invk = 1.0f / (float)k;
#pragma unroll
        for (int j = 0; j < 9; ++j) {
            E.re[j] = Tm.re[j] * invk;
            E.im[j] = Tm.im[j] * invk;
        }
        E.re[0] += 1.f; E.re[4] += 1.f; E.re[8] += 1.f;
    }
#pragma unroll
    for (int q = 0; q < 4; ++q) {
        mmul(Tm, E, E);
        E = Tm;
    }

    // ymu = E @ U  (even site: xmu_fix = 0)
    C3 Y;
    mmul(Y, E, U);

    const int ob = s * 9;            // dir 0 base (complex elements)
#pragma unroll
    for (int j = 0; j < 9; ++j) {
        float2 v; v.x = Y.re[j]; v.y = Y.im[j];
        out[ob + j] = v;
    }
}

extern "C" void kernel_launch(void* const* d_in, const int* in_sizes, int n_in,
                              void* d_out, int out_size, void* d_ws, size_t ws_size,
                              hipStream_t stream) {
    const float* xre   = (const float*)d_in[0];
    const float* xim   = (const float*)d_in[1];
    const float* coeff = (const float*)d_in[2];

    // Pass 1: interleave-copy every link (dirs 0..3) into f32 [.., 3,3,2].
    const int n4 = (4 * NSITE * 9) / 4;   // float4-granular complex elements
    interleave_kernel<<<(n4 + 255) / 256, 256, 0, stream>>>(
        (const float4*)xre, (const float4*)xim, (float4*)d_out, n4);

    // Pass 2: stout-update dir-0 even sites in place.
    stout_kernel<<<(NSITE / 2 + 255) / 256, 256, 0, stream>>>(
        xre, xim, coeff, (float2*)d_out);
}

// Round 4
// 259.318 us; speedup vs baseline: 1.0233x; 1.0233x over previous
//
#include <hip/hip_runtime.h>
#include <cstdint>

#define LT 24
#define NSITE (LT*LT*LT*LT)   // 331776

struct C3 { float re[9]; float im[9]; };

// load matrix from interleaved (re,im) float2 buffer
__device__ __forceinline__ void loadMi(C3& m, const float2* __restrict__ buf, int site) {
    const int base = site * 9;
#pragma unroll
    for (int j = 0; j < 9; ++j) {
        float2 v = buf[base + j];
        m.re[j] = v.x; m.im[j] = v.y;
    }
}

// o = a @ b
__device__ __forceinline__ void mmul(C3& o, const C3& a, const C3& b) {
#pragma unroll
    for (int r = 0; r < 3; ++r) {
#pragma unroll
        for (int c = 0; c < 3; ++c) {
            float sr = 0.f, si = 0.f;
#pragma unroll
            for (int k = 0; k < 3; ++k) {
                float ar = a.re[r*3+k], ai = a.im[r*3+k];
                float br = b.re[k*3+c], bi = b.im[k*3+c];
                sr += ar*br - ai*bi;
                si += ar*bi + ai*br;
            }
            o.re[r*3+c] = sr; o.im[r*3+c] = si;
        }
    }
}

// f += cr * (a @ b)
__device__ __forceinline__ void mmul_acc(C3& f, const C3& a, const C3& b, float cr) {
#pragma unroll
    for (int r = 0; r < 3; ++r) {
#pragma unroll
        for (int c = 0; c < 3; ++c) {
            float sr = 0.f, si = 0.f;
#pragma unroll
            for (int k = 0; k < 3; ++k) {
                float ar = a.re[r*3+k], ai = a.im[r*3+k];
                float br = b.re[k*3+c], bi = b.im[k*3+c];
                sr += ar*br - ai*bi;
                si += ar*bi + ai*br;
            }
            f.re[r*3+c] += cr * sr; f.im[r*3+c] += cr * si;
        }
    }
}

// o = a @ b^dagger
__device__ __forceinline__ void mmul_adjB(C3& o, const C3& a, const C3& b) {
#pragma unroll
    for (int r = 0; r < 3; ++r) {
#pragma unroll
        for (int c = 0; c < 3; ++c) {
            float sr = 0.f, si = 0.f;
#pragma unroll
            for (int k = 0; k < 3; ++k) {
                float ar = a.re[r*3+k], ai = a.im[r*3+k];
                float br = b.re[c*3+k], bi = b.im[c*3+k];
                sr += ar*br + ai*bi;
                si += ai*br - ar*bi;
            }
            o.re[r*3+c] = sr; o.im[r*3+c] = si;
        }
    }
}

// o = a^dagger @ b
__device__ __forceinline__ void madjA_mul(C3& o, const C3& a, const C3& b) {
#pragma unroll
    for (int r = 0; r < 3; ++r) {
#pragma unroll
        for (int c = 0; c < 3; ++c) {
            float sr = 0.f, si = 0.f;
#pragma unroll
            for (int k = 0; k < 3; ++k) {
                float ar = a.re[k*3+r], ai = a.im[k*3+r];
                float br = b.re[k*3+c], bi = b.im[k*3+c];
                sr += ar*br + ai*bi;
                si += ar*bi - ai*br;
            }
            o.re[r*3+c] = sr; o.im[r*3+c] = si;
        }
    }
}

// ---- Kernel 1: fully-coalesced interleave copy ------------------------------
// thread i handles complex elements 2i,2i+1: 8B loads, one 16B store.
__global__ void interleave_kernel(const float2* __restrict__ re,
                                  const float2* __restrict__ im,
                                  float4* __restrict__ out, int n2) {
    int i = blockIdx.x * blockDim.x + threadIdx.x;
    if (i >= n2) return;
    float2 a = re[i], b = im[i];
    float4 o; o.x = a.x; o.y = b.x; o.z = a.y; o.w = b.y;
    out[i] = o;
}

// ---- Kernel 2: stout update on dir-0 even sites, fed from interleaved out ---
__global__ __launch_bounds__(256)
void stout_kernel(const float2* __restrict__ xi,   // interleaved field (=d_out)
                  const float* __restrict__ coeff,
                  float2* __restrict__ out) {
    int tid = blockIdx.x * blockDim.x + threadIdx.x;
    if (tid >= NSITE / 2) return;

    int xh = tid % 12;  int r0 = tid / 12;
    int y  = r0 % LT;   r0 /= LT;
    int z  = r0 % LT;   int t = r0 / LT;
    int x  = 2 * xh + ((t + z + y) & 1);   // even-parity site

    // scaled coefficients: (2/pi)*0.75*atan(coeff)/6
    float c[6];
#pragma unroll
    for (int i = 0; i < 6; ++i)
        c[i] = 0.07957747154594768f * atanf(coeff[i]);

    int tp = (t + 1 < LT) ? t + 1 : 0;
    int zp = (z + 1 < LT) ? z + 1 : 0;  int zm = (z > 0) ? z - 1 : LT - 1;
    int yp = (y + 1 < LT) ? y + 1 : 0;  int ym = (y > 0) ? y - 1 : LT - 1;
    int xp = (x + 1 < LT) ? x + 1 : 0;  int xm = (x > 0) ? x - 1 : LT - 1;

    const int s   = ((t  * LT + z) * LT + y) * LT + x;
    const int stt = ((tp * LT + z) * LT + y) * LT + x;   // s + T^
    const int spv[3]  = { ((t  * LT + zp) * LT + y ) * LT + x,
                          ((t  * LT + z ) * LT + yp) * LT + x,
                          ((t  * LT + z ) * LT + y ) * LT + xp };
    const int smv[3]  = { ((t  * LT + zm) * LT + y ) * LT + x,
                          ((t  * LT + z ) * LT + ym) * LT + x,
                          ((t  * LT + z ) * LT + y ) * LT + xm };
    const int smtv[3] = { ((tp * LT + zm) * LT + y ) * LT + x,
                          ((tp * LT + z ) * LT + ym) * LT + x,
                          ((tp * LT + z ) * LT + y ) * LT + xm };

    C3 f;
#pragma unroll
    for (int j = 0; j < 9; ++j) { f.re[j] = 0.f; f.im[j] = 0.f; }

    C3 A, B, Cm, tmp;
#pragma unroll
    for (int i = 0; i < 3; ++i) {
        const int d = i + 1;
        // forward staple: x[nu](s) @ x0(s+nu) @ x[nu](s+T)^dag
        loadMi(B,  xi, spv[i]);            // dir 0
        loadMi(Cm, xi, d * NSITE + stt);
        loadMi(A,  xi, d * NSITE + s);
        mmul_adjB(tmp, B, Cm);
        mmul_acc(f, A, tmp, c[2 * i]);
        // backward staple: x[nu](s-nu)^dag @ x0(s-nu) @ x[nu](s-nu+T)
        loadMi(A,  xi, d * NSITE + smv[i]);
        loadMi(B,  xi, smv[i]);            // dir 0
        loadMi(Cm, xi, d * NSITE + smtv[i]);
        madjA_mul(tmp, A, B);
        mmul_acc(f, tmp, Cm, c[2 * i + 1]);
    }

    // xupd = x0(s) (even site)
    C3 U;
    loadMi(U, xi, s);

    // M = f @ U^dag ; A = 0.5(M - M^dag) ; Zt = A - tr(A)/3 * I
    C3 Mm;
    mmul_adjB(Mm, f, U);
    C3 Zt;
#pragma unroll
    for (int r = 0; r < 3; ++r) {
#pragma unroll
        for (int cq = 0; cq < 3; ++cq) {
            Zt.re[r*3+cq] = 0.5f * (Mm.re[r*3+cq] - Mm.re[cq*3+r]);
            Zt.im[r*3+cq] = 0.5f * (Mm.im[r*3+cq] + Mm.im[cq*3+r]);
        }
    }
    float trIm = (Zt.im[0] + Zt.im[4] + Zt.im[8]) / 3.0f;
    Zt.im[0] -= trIm; Zt.im[4] -= trIm; Zt.im[8] -= trIm;

    // matexp: scale by 0.5^4, 12-term Horner, 4 squarings
#pragma unroll
    for (int j = 0; j < 9; ++j) { Zt.re[j] *= 0.0625f; Zt.im[j] *= 0.0625f; }

    C3 E;
#pragma unroll
    for (int j = 0; j < 9; ++j) { E.re[j] = 0.f; E.im[j] = 0.f; }
    E.re[0] = 1.f; E.re[4] = 1.f; E.re[8] = 1.f;

    C3 Tm;
#pragma unroll
    for (int k = 12; k >= 1; --k) {
        mmul(Tm, Zt, E);
        const float invk = 1.0f / (float)k;
#pragma unroll
        for (int j = 0; j < 9; ++j) {
            E.re[j] = Tm.re[j] * invk;
            E.im[j] = Tm.im[j] * invk;
        }
        E.re[0] += 1.f; E.re[4] += 1.f; E.re[8] += 1.f;
    }
#pragma unroll
    for (int q = 0; q < 4; ++q) {
        mmul(Tm, E, E);
        E = Tm;
    }

    // ymu = E @ U  (even site: xmu_fix = 0)
    C3 Y;
    mmul(Y, E, U);

    const int ob = s * 9;            // dir 0 base (complex elements)
#pragma unroll
    for (int j = 0; j < 9; ++j) {
        float2 v; v.x = Y.re[j]; v.y = Y.im[j];
        out[ob + j] = v;
    }
}

extern "C" void kernel_launch(void* const* d_in, const int* in_sizes, int n_in,
                              void* d_out, int out_size, void* d_ws, size_t ws_size,
                              hipStream_t stream) {
    const float* xre   = (const float*)d_in[0];
    const float* xim   = (const float*)d_in[1];
    const float* coeff = (const float*)d_in[2];

    // Pass 1: interleave-copy every link (dirs 0..3) into f32 [.., 3,3,2].
    const int n2 = (4 * NSITE * 9) / 2;   // 2 complex elements per thread
    interleave_kernel<<<(n2 + 255) / 256, 256, 0, stream>>>(
        (const float2*)xre, (const float2*)xim, (float4*)d_out, n2);

    // Pass 2: stout-update dir-0 even sites, reading the interleaved copy.
    stout_kernel<<<(NSITE / 2 + 255) / 256, 256, 0, stream>>>(
        (const float2*)d_out, coeff, (float2*)d_out);
}

// Round 5
// 249.354 us; speedup vs baseline: 1.0642x; 1.0400x over previous
//
#include <hip/hip_runtime.h>
#include <cstdint>

#define LT 24
#define NSITE (LT*LT*LT*LT)   // 331776

struct C3 { float re[9]; float im[9]; };

// 9 contiguous floats, base only guaranteed 4B-aligned:
// two unaligned 16B loads + one scalar (gfx9+ lowers align-4 16B to dwordx4).
__device__ __forceinline__ void load9(float* d, const float* __restrict__ p) {
    float4 a, b;
    __builtin_memcpy(&a, p,     16);
    __builtin_memcpy(&b, p + 4, 16);
    d[0]=a.x; d[1]=a.y; d[2]=a.z; d[3]=a.w;
    d[4]=b.x; d[5]=b.y; d[6]=b.z; d[7]=b.w;
    d[8]=p[8];
}

__device__ __forceinline__ void loadM(C3& m, const float* __restrict__ re,
                                      const float* __restrict__ im, int off) {
    load9(m.re, re + off);
    load9(m.im, im + off);
}

// store matrix as interleaved (re,im) pairs at complex-element base cbase
// (byte base = 8*cbase, 8B-aligned): 4 x 16B + 1 x 8B stores.
__device__ __forceinline__ void storeM(float2* __restrict__ out, int cbase, const C3& m) {
    float4 v;
    v.x=m.re[0]; v.y=m.im[0]; v.z=m.re[1]; v.w=m.im[1];
    __builtin_memcpy(out + cbase,     &v, 16);
    v.x=m.re[2]; v.y=m.im[2]; v.z=m.re[3]; v.w=m.im[3];
    __builtin_memcpy(out + cbase + 2, &v, 16);
    v.x=m.re[4]; v.y=m.im[4]; v.z=m.re[5]; v.w=m.im[5];
    __builtin_memcpy(out + cbase + 4, &v, 16);
    v.x=m.re[6]; v.y=m.im[6]; v.z=m.re[7]; v.w=m.im[7];
    __builtin_memcpy(out + cbase + 6, &v, 16);
    float2 w; w.x=m.re[8]; w.y=m.im[8];
    out[cbase + 8] = w;
}

// o = a @ b
__device__ __forceinline__ void mmul(C3& o, const C3& a, const C3& b) {
#pragma unroll
    for (int r = 0; r < 3; ++r) {
#pragma unroll
        for (int c = 0; c < 3; ++c) {
            float sr = 0.f, si = 0.f;
#pragma unroll
            for (int k = 0; k < 3; ++k) {
                float ar = a.re[r*3+k], ai = a.im[r*3+k];
                float br = b.re[k*3+c], bi = b.im[k*3+c];
                sr += ar*br - ai*bi;
                si += ar*bi + ai*br;
            }
            o.re[r*3+c] = sr; o.im[r*3+c] = si;
        }
    }
}

// f += cr * (a @ b)
__device__ __forceinline__ void mmul_acc(C3& f, const C3& a, const C3& b, float cr) {
#pragma unroll
    for (int r = 0; r < 3; ++r) {
#pragma unroll
        for (int c = 0; c < 3; ++c) {
            float sr = 0.f, si = 0.f;
#pragma unroll
            for (int k = 0; k < 3; ++k) {
                float ar = a.re[r*3+k], ai = a.im[r*3+k];
                float br = b.re[k*3+c], bi = b.im[k*3+c];
                sr += ar*br - ai*bi;
                si += ar*bi + ai*br;
            }
            f.re[r*3+c] += cr * sr; f.im[r*3+c] += cr * si;
        }
    }
}

// o = a @ b^dagger
__device__ __forceinline__ void mmul_adjB(C3& o, const C3& a, const C3& b) {
#pragma unroll
    for (int r = 0; r < 3; ++r) {
#pragma unroll
        for (int c = 0; c < 3; ++c) {
            float sr = 0.f, si = 0.f;
#pragma unroll
            for (int k = 0; k < 3; ++k) {
                float ar = a.re[r*3+k], ai = a.im[r*3+k];
                float br = b.re[c*3+k], bi = b.im[c*3+k];
                sr += ar*br + ai*bi;
                si += ai*br - ar*bi;
            }
            o.re[r*3+c] = sr; o.im[r*3+c] = si;
        }
    }
}

// o = a^dagger @ b
__device__ __forceinline__ void madjA_mul(C3& o, const C3& a, const C3& b) {
#pragma unroll
    for (int r = 0; r < 3; ++r) {
#pragma unroll
        for (int c = 0; c < 3; ++c) {
            float sr = 0.f, si = 0.f;
#pragma unroll
            for (int k = 0; k < 3; ++k) {
                float ar = a.re[k*3+r], ai = a.im[k*3+r];
                float br = b.re[k*3+c], bi = b.im[k*3+c];
                sr += ar*br + ai*bi;
                si += ar*bi - ai*br;
            }
            o.re[r*3+c] = sr; o.im[r*3+c] = si;
        }
    }
}

// idx in [0, NSITE/2) -> site of given parity (0=even updated subset, 1=odd)
__device__ __forceinline__ int site_from_idx(int idx, int parity,
                                             int& t, int& z, int& y, int& x) {
    int xh = idx % 12;  int r = idx / 12;
    y = r % LT; r /= LT;
    z = r % LT; t = r / LT;
    x = 2 * xh + ((t + z + y + parity) & 1);
    return ((t * LT + z) * LT + y) * LT + x;
}

// ---- Fused kernel ----------------------------------------------------------
// Block of 256: waves 0-1 -> 128 even sites (stout update + copy dirs 1-3),
//               waves 2-3 -> 128 odd sites (copy all 4 dirs).
__global__ __launch_bounds__(256)
void stout_fused(const float* __restrict__ xre, const float* __restrict__ xim,
                 const float* __restrict__ coeff, float2* __restrict__ out) {
    const int tau = threadIdx.x;
    const bool heavy = (tau < 128);
    const int idx = blockIdx.x * 128 + (heavy ? tau : tau - 128);

    if (!heavy) {
        // ---- odd-site pass-through copy, all 4 directions ----
        int t, z, y, x;
        const int s = site_from_idx(idx, 1, t, z, y, x);
        C3 m;
#pragma unroll
        for (int d = 0; d < 4; ++d) {
            const int off = (d * NSITE + s) * 9;
            loadM(m, xre, xim, off);
            storeM(out, off, m);
        }
        return;
    }

    // ---- even-site stout update + copy of this site's dirs 1-3 ----
    int t, z, y, x;
    const int s = site_from_idx(idx, 0, t, z, y, x);

    // scaled coefficients: (2/pi)*0.75*atan(coeff)/6
    float c[6];
#pragma unroll
    for (int i = 0; i < 6; ++i)
        c[i] = 0.07957747154594768f * atanf(coeff[i]);

    int tp = (t + 1 < LT) ? t + 1 : 0;
    int zp = (z + 1 < LT) ? z + 1 : 0;  int zm = (z > 0) ? z - 1 : LT - 1;
    int yp = (y + 1 < LT) ? y + 1 : 0;  int ym = (y > 0) ? y - 1 : LT - 1;
    int xp = (x + 1 < LT) ? x + 1 : 0;  int xm = (x > 0) ? x - 1 : LT - 1;

    const int stt = ((tp * LT + z) * LT + y) * LT + x;   // s + T^
    const int spv[3]  = { ((t  * LT + zp) * LT + y ) * LT + x,
                          ((t  * LT + z ) * LT + yp) * LT + x,
                          ((t  * LT + z ) * LT + y ) * LT + xp };
    const int smv[3]  = { ((t  * LT + zm) * LT + y ) * LT + x,
                          ((t  * LT + z ) * LT + ym) * LT + x,
                          ((t  * LT + z ) * LT + y ) * LT + xm };
    const int smtv[3] = { ((tp * LT + zm) * LT + y ) * LT + x,
                          ((tp * LT + z ) * LT + ym) * LT + x,
                          ((tp * LT + z ) * LT + y ) * LT + xm };

    C3 f;
#pragma unroll
    for (int j = 0; j < 9; ++j) { f.re[j] = 0.f; f.im[j] = 0.f; }

    C3 A, B, Cm, tmp;
#pragma unroll
    for (int i = 0; i < 3; ++i) {
        const int d = i + 1;
        // forward staple: x[nu](s) @ x0(s+nu) @ x[nu](s+T)^dag
        loadM(A, xre, xim, (d * NSITE + s) * 9);
        storeM(out, (d * NSITE + s) * 9, A);          // pass-through copy dir nu
        loadM(B,  xre, xim, (     spv[i])        * 9);  // dir 0, odd neighbor
        loadM(Cm, xre, xim, (d * NSITE + stt)    * 9);
        mmul_adjB(tmp, B, Cm);
        mmul_acc(f, A, tmp, c[2 * i]);
        // backward staple: x[nu](s-nu)^dag @ x0(s-nu) @ x[nu](s-nu+T)
        loadM(A,  xre, xim, (d * NSITE + smv[i]) * 9);
        loadM(B,  xre, xim, (     smv[i])        * 9);  // dir 0, odd neighbor
        loadM(Cm, xre, xim, (d * NSITE + smtv[i])* 9);
        madjA_mul(tmp, A, B);
        mmul_acc(f, tmp, Cm, c[2 * i + 1]);
    }

    // xupd = x0(s) (even site)
    C3 U;
    loadM(U, xre, xim, s * 9);

    // M = f @ U^dag ; A = 0.5(M - M^dag) ; Zt = A - tr(A)/3 * I
    C3 Mm;
    mmul_adjB(Mm, f, U);
    C3 Zt;
#pragma unroll
    for (int r = 0; r < 3; ++r) {
#pragma unroll
        for (int cq = 0; cq < 3; ++cq) {
            Zt.re[r*3+cq] = 0.5f * (Mm.re[r*3+cq] - Mm.re[cq*3+r]);
            Zt.im[r*3+cq] = 0.5f * (Mm.im[r*3+cq] + Mm.im[cq*3+r]);
        }
    }
    float trIm = (Zt.im[0] + Zt.im[4] + Zt.im[8]) / 3.0f;
    Zt.im[0] -= trIm; Zt.im[4] -= trIm; Zt.im[8] -= trIm;

    // matexp: scale by 0.5^4, 12-term Horner, 4 squarings
#pragma unroll
    for (int j = 0; j < 9; ++j) { Zt.re[j] *= 0.0625f; Zt.im[j] *= 0.0625f; }

    C3 E;
#pragma unroll
    for (int j = 0; j < 9; ++j) { E.re[j] = 0.f; E.im[j] = 0.f; }
    E.re[0] = 1.f; E.re[4] = 1.f; E.re[8] = 1.f;

    C3 Tm;
#pragma unroll
    for (int k = 12; k >= 1; --k) {
        mmul(Tm, Zt, E);
        const float invk = 1.0f / (float)k;
#pragma unroll
        for (int j = 0; j < 9; ++j) {
            E.re[j] = Tm.re[j] * invk;
            E.im[j] = Tm.im[j] * invk;
        }
        E.re[0] += 1.f; E.re[4] += 1.f; E.re[8] += 1.f;
    }
#pragma unroll
    for (int q = 0; q < 4; ++q) {
        mmul(Tm, E, E);
        E = Tm;
    }

    // ymu = E @ U  (even site: xmu_fix = 0)
    C3 Y;
    mmul(Y, E, U);
    storeM(out, s * 9, Y);   // dir 0 updated link
}

extern "C" void kernel_launch(void* const* d_in, const int* in_sizes, int n_in,
                              void* d_out, int out_size, void* d_ws, size_t ws_size,
                              hipStream_t stream) {
    const float* xre   = (const float*)d_in[0];
    const float* xim   = (const float*)d_in[1];
    const float* coeff = (const float*)d_in[2];

    const int nblocks = (NSITE / 2) / 128;   // 1296
    stout_fused<<<nblocks, 256, 0, stream>>>(xre, xim, coeff, (float2*)d_out);
}